// Round 8
// baseline (155.976 us; speedup 1.0000x reference)
//
#include <hip/hip_runtime.h>
#include <hip/hip_fp16.h>
#include <stdint.h>

#define LOSS_IDX 8388608
#define IDX_BASE 8388609

typedef _Float16 half8 __attribute__((ext_vector_type(8)));
typedef float f32x4 __attribute__((ext_vector_type(4)));
typedef unsigned long long u64;

// ---- workspace layout (bytes) ----
#define WIN_OFF   0            // 32768 * 8  winner (key<<32 | k)
#define E2_OFF    262144       // 1024 * 4   code norms
#define ETILE_OFF 266240       // 32 images * 40960 B  pre-tiled fp16 hi/lo emb
// image (cg,cc): [hi: 256 rows * 80 B][lo: 256 rows * 80 B]
// row = 32 c halfs in four 16B chunks, chunk XOR-swizzled by (row>>3)&3, +16B pad

static __device__ __forceinline__ unsigned fkey(float d) {
    unsigned u = __float_as_uint(d);
    return u ^ ((unsigned)(((int)u) >> 31) | 0x80000000u);
}

// ---------------------------------------------------------------------------
// K0: e2 norms, emb -> pre-tiled fp16 hi/lo planes (XOR chunk swizzle baked
// into the global layout), winner init, loss=0. (ROUND-2 VERBATIM — verified.)
// ---------------------------------------------------------------------------
__global__ __launch_bounds__(256) void k0_prep(
    const float* __restrict__ emb, float* __restrict__ e2,
    ushort* __restrict__ etile, unsigned* __restrict__ win32,
    float* __restrict__ out) {
    int tid = blockIdx.x * 256 + threadIdx.x;      // 0..65535
    win32[tid] = 0xFFFFFFFFu;                      // win64 = all-ones
    if (tid == 0) out[LOSS_IDX] = 0.f;             // re-zero every call
    int code = tid >> 6;                           // 0..1023
    int lane = tid & 63;
    const float4 v4 = *(const float4*)&emb[code * 256 + lane * 4];
    float vv[4] = {v4.x, v4.y, v4.z, v4.w};
    float s = vv[0]*vv[0] + vv[1]*vv[1] + vv[2]*vv[2] + vv[3]*vv[3];
    #pragma unroll
    for (int off = 32; off > 0; off >>= 1) s += __shfl_down(s, off, 64);
    if (lane == 0) e2[code] = s;
    int cg = code >> 8, n = code & 255;            // 4 groups of 256 codes
    int xs = (n >> 3) & 3;                         // row-octet XOR swizzle
    #pragma unroll
    for (int i = 0; i < 4; ++i) {
        int c = lane * 4 + i;
        float v = vv[i];
        __half h = __float2half(v);                       // RNE
        __half l = __float2half(v - __half2float(h));     // residual
        int cc = c >> 5, cw = c & 31;
        int ch = (cw >> 3) ^ xs;                          // swizzled 16B chunk
        int hoff = (cg * 8 + cc) * 20480 + n * 40 + ch * 8 + (cw & 7);
        etile[hoff] = __half_as_ushort(h);                // hi plane
        etile[hoff + 10240] = __half_as_ushort(l);        // lo plane
    }
}

// ---------------------------------------------------------------------------
// K2: fp16x3 MFMA distance GEMM + fused argmin — COUNTED-VMCNT PIPELINE.
// 512 thr / 8 waves, tile 128 q x 256 codes, grid 1024 XCD-grouped.
// Triple-rotated e-buffers, prefetch distance 2:
//   chunk cc: [issue z(cc+1) loads | issue e-DMA(cc+2) | ds_read frags(cc) |
//              48 MFMA | write_z(cc+1)] lgkmcnt(0) + RAW s_barrier.
// vmcnt is NEVER drained to 0 in the loop: the compiler's own zv-wait is
// vmcnt(5) (in-order queue [DMA(cc+1):5, z:8, DMA(cc+2):5]) which drains
// DMA(cc+1)+z and leaves DMA(cc+2) flying across the barrier with ~2 chunks
// of latency cover. __syncthreads' implicit vmcnt(0) (present in rounds 0-3,
// the m97-documented ~30-40% drain stall) is thereby eliminated.
// Cross-wave safety: every wave drains DMA(cc+1) (zv-wait) + its ds_writes
// (lgkmcnt) BEFORE its barrier; buffer read in chunk cc+1 is never the
// buffer DMA'd in chunk cc. LDS = 3*40960 + 4*10240 = 163840 B (full 160K);
// e2 lives in 4 regs/thread, z2-reduce reuses dead z LDS.
// ---------------------------------------------------------------------------
__global__ __launch_bounds__(512, 2) void k2_mfma(
    const float* __restrict__ z_e, const float* __restrict__ e2g,
    const ushort* __restrict__ etile, u64* __restrict__ win64,
    float* __restrict__ out) {
    __shared__ __attribute__((aligned(16))) ushort zh_s[2][5120];
    __shared__ __attribute__((aligned(16))) ushort zl_s[2][5120];
    __shared__ __attribute__((aligned(16))) ushort ehl_s[3][20480];

    int t = threadIdx.x;
    int lane = t & 63;
    int w = t >> 6;
    int i0 = blockIdx.x;
    int cg = (i0 >> 3) & 3;             // code group: 256 codes
    int qg = (i0 & 7) + (i0 >> 5) * 8;  // query group: 128 q (XCD-grouped)
    int qbase = qg * 128;
    int b = qbase >> 10;
    int hw0 = qbase & 1023;
    const float* zb = z_e + b * (256 * 1024) + hw0;

    int qh = w >> 2, nqr = w & 3;   // wave tile: 64 q x 64 codes
    int lm = lane & 15, kq = lane >> 4;

    float e2r[4];                   // e2 for this thread's 4 epilogue codes
    #pragma unroll
    for (int nt = 0; nt < 4; ++nt)
        e2r[nt] = e2g[cg * 256 + nqr * 64 + nt * 16 + lm];

    f32x4 acc[4][4];
    #pragma unroll
    for (int mt = 0; mt < 4; ++mt)
        #pragma unroll
        for (int nt = 0; nt < 4; ++nt) acc[mt][nt] = (f32x4){0.f, 0.f, 0.f, 0.f};

    int qz = t & 127, sz = t >> 7;  // staging: q row fixed, chunk sz (0..3)
    float z2acc = 0.f;

    // ---- helpers (all callers pass compile-time cc/buf) ----
    auto stage_e = [&](int cc2, int buf) {
        const char* gsrc = (const char*)etile + (size_t)(cg * 8 + cc2) * 40960;
        char* ldst = (char*)&ehl_s[buf][0];
        #pragma unroll
        for (int i = 0; i < 5; ++i) {
            int off = (i * 512 + t) * 16;
            __builtin_amdgcn_global_load_lds(
                (const __attribute__((address_space(1))) unsigned int*)(gsrc + off),
                (__attribute__((address_space(3))) unsigned int*)(ldst + off),
                16, 0, 0);
        }
    };
    auto load_z = [&](int cc2, float* v) {
        int c0 = cc2 * 32 + 8 * sz;         // thread owns 8 consecutive c
        #pragma unroll
        for (int i = 0; i < 4; ++i) {
            int c = c0 + 2 * i;
            v[2 * i]     = zb[c * 1024 + qz];
            v[2 * i + 1] = zb[(c + 1) * 1024 + qz];
        }
    };
    auto write_z = [&](const float* v, int buf) {
        unsigned wh[4], wl[4];
        #pragma unroll
        for (int i = 0; i < 4; ++i) {
            float v0 = v[2 * i], v1 = v[2 * i + 1];
            z2acc = fmaf(v0, v0, z2acc);
            z2acc = fmaf(v1, v1, z2acc);
            __half h0 = __float2half(v0), h1 = __float2half(v1);
            __half l0 = __float2half(v0 - __half2float(h0));
            __half l1 = __float2half(v1 - __half2float(h1));
            wh[i] = (unsigned)__half_as_ushort(h0) | ((unsigned)__half_as_ushort(h1) << 16);
            wl[i] = (unsigned)__half_as_ushort(l0) | ((unsigned)__half_as_ushort(l1) << 16);
        }
        int ch = sz ^ ((qz >> 3) & 3);       // chunk XOR swizzle
        int idx = qz * 5 + ch;               // uint4 units (row = 20 words)
        ((uint4*)&zh_s[buf][0])[idx] = make_uint4(wh[0], wh[1], wh[2], wh[3]);
        ((uint4*)&zl_s[buf][0])[idx] = make_uint4(wl[0], wl[1], wl[2], wl[3]);
    };

    // ---- prologue: z0 + DMA(0,1); drain DMA0 only; DMA1 stays in flight ----
    float zv[8];
    load_z(0, zv);                           // oldest vmcnt slots
    asm volatile("" ::: "memory");           // pin z-loads before DMA issue
    stage_e(0, 0);
    stage_e(1, 1);
    write_z(zv, 0);                          // compiler waits zv (vmcnt(10))
    asm volatile("s_waitcnt vmcnt(5)" ::: "memory");   // DMA0 landed
    asm volatile("s_waitcnt lgkmcnt(0)" ::: "memory"); // ds_writes visible
    __builtin_amdgcn_s_barrier();
    asm volatile("" ::: "memory");

    // ---- main loop: fully unrolled (static buffer indices) ----
    #pragma unroll
    for (int cc = 0; cc < 8; ++cc) {
        const int cur = cc & 1, nxt = cur ^ 1, eb = cc % 3;
        if (cc < 7) {
            load_z(cc + 1, zv);              // issue FIRST (oldest slots)
            asm volatile("" ::: "memory");   // keep before DMA issue
        }
        if (cc < 6) stage_e(cc + 2, (cc + 2) % 3);   // flies across barrier
        half8 ah[4], al[4], bh[4], bl[4];
        #pragma unroll
        for (int mt = 0; mt < 4; ++mt) {
            int q = qh * 64 + mt * 16 + lm;
            int ch = kq ^ ((q >> 3) & 3);
            ah[mt] = *(const half8*)&zh_s[cur][q * 40 + ch * 8];
            al[mt] = *(const half8*)&zl_s[cur][q * 40 + ch * 8];
        }
        #pragma unroll
        for (int nt = 0; nt < 4; ++nt) {
            int n = nqr * 64 + nt * 16 + lm;
            int ech = kq ^ ((n >> 3) & 3);   // matches k0 layout
            bh[nt] = *(const half8*)&ehl_s[eb][n * 40 + ech * 8];
            bl[nt] = *(const half8*)&ehl_s[eb][10240 + n * 40 + ech * 8];
        }
        __builtin_amdgcn_s_setprio(1);
        // three passes of 16 independent MFMAs (acc reuse distance 16)
        #pragma unroll
        for (int nt = 0; nt < 4; ++nt)
            #pragma unroll
            for (int mt = 0; mt < 4; ++mt)
                acc[mt][nt] = __builtin_amdgcn_mfma_f32_16x16x32_f16(ah[mt], bh[nt], acc[mt][nt], 0, 0, 0);
        #pragma unroll
        for (int nt = 0; nt < 4; ++nt)
            #pragma unroll
            for (int mt = 0; mt < 4; ++mt)
                acc[mt][nt] = __builtin_amdgcn_mfma_f32_16x16x32_f16(ah[mt], bl[nt], acc[mt][nt], 0, 0, 0);
        #pragma unroll
        for (int nt = 0; nt < 4; ++nt)
            #pragma unroll
            for (int mt = 0; mt < 4; ++mt)
                acc[mt][nt] = __builtin_amdgcn_mfma_f32_16x16x32_f16(al[mt], bh[nt], acc[mt][nt], 0, 0, 0);
        __builtin_amdgcn_s_setprio(0);
        if (cc < 7) {
            write_z(zv, nxt);                // compiler's zv-wait = vmcnt(5):
                                             // drains DMA(cc+1)+z, NOT DMA(cc+2)
            asm volatile("s_waitcnt lgkmcnt(0)" ::: "memory");
            __builtin_amdgcn_s_barrier();    // raw: no vmcnt(0) drain
            asm volatile("" ::: "memory");
        }
    }

    // ---- argmin epilogue: C layout col=lane&15 (code), row=(lane>>4)*4+r (q)
    int lg = lane >> 4;
    #pragma unroll
    for (int mt = 0; mt < 4; ++mt)
        #pragma unroll
        for (int r = 0; r < 4; ++r) {
            int qloc = qh * 64 + mt * 16 + lg * 4 + r;
            u64 best = ~0ull;
            #pragma unroll
            for (int nt = 0; nt < 4; ++nt) {
                int nloc = nqr * 64 + nt * 16 + lm;
                float d = fmaf(-2.f, acc[mt][nt][r], e2r[nt]);
                u64 p = ((u64)fkey(d) << 32) | (unsigned)(cg * 256 + nloc);
                if (p < best) best = p;
            }
            #pragma unroll
            for (int m = 1; m <= 8; m <<= 1) {     // reduce over 16 code-lanes
                unsigned blo = __shfl_xor((unsigned)best, m, 64);
                unsigned bhi = __shfl_xor((unsigned)(best >> 32), m, 64);
                u64 p = ((u64)bhi << 32) | blo;
                if (p < best) best = p;
            }
            if (lm == 0) atomicMin(&win64[qbase + qloc], best);
        }

    // ---- sum(z^2) loss contribution (count once: cg==0 blocks) ----
    #pragma unroll
    for (int off = 32; off > 0; off >>= 1) z2acc += __shfl_down(z2acc, off, 64);
    __syncthreads();                    // full drain OK at kernel end
    float* red = (float*)&zh_s[0][0];   // reuse dead z LDS
    if (lane == 0) red[w] = z2acc;
    __syncthreads();
    if (t == 0 && cg == 0) {
        float s = 0.f;
        #pragma unroll
        for (int i = 0; i < 8; ++i) s += red[i];
        atomicAdd(&out[LOSS_IDX], s * (1.25f / 8388608.f));
    }
}

// ---------------------------------------------------------------------------
// K3: res = emb[k*] scattered to (b,c,h,w); indices as float; loss part 2
// recovered from the winner key. (ROUND-0 VERBATIM.)
// ---------------------------------------------------------------------------
__global__ __launch_bounds__(256, 2) void k3_out(
    const float* __restrict__ emb, const u64* __restrict__ win64,
    float* __restrict__ out) {
    __shared__ float lde[64 * 257];
    __shared__ int lwin[64];
    int t = threadIdx.x;
    int qbase = blockIdx.x * 64;
    int b = qbase >> 10;
    int hw0 = qbase & 1023;
    if (t < 64) {                                  // wave 0 only (uniform)
        u64 p = win64[qbase + t];
        int k = (int)(p & 0xFFFFFFFFull);
        lwin[t] = k;
        out[IDX_BASE + qbase + t] = (float)k;
        unsigned key = (unsigned)(p >> 32);
        unsigned u = (key & 0x80000000u) ? (key ^ 0x80000000u) : ~key;
        float dval = __uint_as_float(u);
        #pragma unroll
        for (int off = 32; off > 0; off >>= 1) dval += __shfl_down(dval, off, 64);
        if (t == 0) atomicAdd(&out[LOSS_IDX], dval * (1.25f / 8388608.f));
    }
    __syncthreads();
    for (int i = 0; i < 64; ++i)                   // coalesced 1 KB row loads
        lde[i * 257 + t] = emb[lwin[i] * 256 + t];
    __syncthreads();
    float* rb = out + b * (256 * 1024) + hw0;
    int j = t & 63, chi = t >> 6;
    #pragma unroll 4
    for (int p = 0; p < 64; ++p) {
        int c = p * 4 + chi;
        rb[c * 1024 + j] = lde[j * 257 + c];       // 2-way banks (free)
    }
}

// ---------------------------------------------------------------------------
extern "C" void kernel_launch(void* const* d_in, const int* in_sizes, int n_in,
                              void* d_out, int out_size, void* d_ws, size_t ws_size,
                              hipStream_t stream) {
    const float* z_e = (const float*)d_in[0];   // (32,256,32,32) fp32
    const float* emb = (const float*)d_in[1];   // (1024,256) fp32
    float* out = (float*)d_out;                 // res | loss | indices(float)
    u64*    win   = (u64*)((char*)d_ws + WIN_OFF);
    float*  e2    = (float*)((char*)d_ws + E2_OFF);
    ushort* etile = (ushort*)((char*)d_ws + ETILE_OFF);

    k0_prep<<<256, 256, 0, stream>>>(emb, e2, etile, (unsigned*)win, out);
    k2_mfma<<<1024, 512, 0, stream>>>(z_e, e2, etile, win, out);
    k3_out <<<512, 256, 0, stream>>>(emb, win, out);
}